// Round 14
// baseline (351.954 us; speedup 1.0000x reference)
//
#include <hip/hip_runtime.h>
#include <math.h>

typedef _Float16 f16x8 __attribute__((ext_vector_type(8)));
typedef float f32x4 __attribute__((ext_vector_type(4)));
typedef unsigned short ushort_t;

constexpr int HWp = 2304;
constexpr float EPS = 1e-5f;

// ws layout (bytes): w1h@0, w1l@65536, w2h@131072, w2l@196608 (fp16, 32768 each)
//   qkBh@262144 (4096), qkBl@266240 (4096), qb2@270336 (64), peG@270400 (3072)
//   w_m0P@273472 (131072), w_m1P@404544 (131072), o_ws@535616 (4718592)
constexpr size_t M0P_OFF = 273472;
constexpr size_t M1P_OFF = 404544;
constexpr size_t OWS_OFF = 535616;

// swizzled ushort index, 256B rows (128 fp16 cols): byte = row*256 + ((c*2)^((row&7)<<4))
__device__ __forceinline__ int sidx(int row, int c) {
    return ((row << 8) + ((c << 1) ^ ((row & 7) << 4))) >> 1;
}
// swizzled ushort index, 128B rows (64 fp16 cols)
__device__ __forceinline__ int sidx2(int row, int c) {
    return ((row << 7) + ((c << 1) ^ ((row & 7) << 4))) >> 1;
}

// ---------------- prep: weights -> split fp16, fold Q+scale, PE table, mlp weight transpose ----------------
__global__ void ltae_prep(const float* __restrict__ w_in0, const float* __restrict__ w_in1,
                          const float* __restrict__ Qm, const float* __restrict__ w_k,
                          const float* __restrict__ b_k, const int* __restrict__ bpos,
                          const float* __restrict__ w_m0, const float* __restrict__ w_m1,
                          _Float16* __restrict__ w1h, _Float16* __restrict__ w1l,
                          _Float16* __restrict__ w2h, _Float16* __restrict__ w2l,
                          _Float16* __restrict__ qkBh, _Float16* __restrict__ qkBl,
                          float* __restrict__ qb2G, float* __restrict__ peG,
                          float* __restrict__ w_m0P, float* __restrict__ w_m1P) {
    int i = blockIdx.x * 256 + threadIdx.x;
    if (i < 32768) {
        float v = w_in0[i];
        _Float16 h = (_Float16)v;
        w1h[i] = h; w1l[i] = (_Float16)(v - (float)h);
    } else if (i < 65536) {
        int j = i - 32768;
        float v = w_in1[j];
        _Float16 h = (_Float16)v;
        w2h[j] = h; w2l[j] = (_Float16)(v - (float)h);
    } else if (i < 67584) {
        int j = i - 65536; int h = j >> 7, k = j & 127;
        float s = 0.f;
        #pragma unroll
        for (int dk = 0; dk < 4; dk++) s = fmaf(Qm[h * 4 + dk], w_k[(h * 4 + dk) * 128 + k], s);
        s *= 0.5f;
        _Float16 hi = (_Float16)s;
        int ks = k >> 5, lg = (k >> 3) & 3, jj = k & 7;
        int pos = ((ks * 4 + lg) * 16 + h) * 8 + jj;
        qkBh[pos] = hi; qkBl[pos] = (_Float16)(s - (float)hi);
    } else if (i < 67600) {
        int h = i - 67584;
        float s = 0.f;
        #pragma unroll
        for (int dk = 0; dk < 4; dk++) s = fmaf(Qm[h * 4 + dk], b_k[h * 4 + dk], s);
        qb2G[h] = 0.5f * s;
    } else if (i < 68368) {
        int j = i - 67600;
        int bb = j / 192, r = j - bb * 192;
        int t = r >> 3, d = r & 7;
        const float dens[4] = {1.0f, 5.623413251903491f, 31.622776601683793f, 177.82794100389228f};
        float ang = (float)bpos[bb * 24 + t] / dens[d >> 1];
        peG[j] = (d & 1) ? cosf(ang) : sinf(ang);
    } else if (i < 101136) {
        int j = i - 68368;                  // j = c2*512 + o*2 + jj (c2<64, o<256)
        int c2 = j >> 9, rem = j & 511, o = rem >> 1, jj = rem & 1;
        w_m0P[j] = w_m0[o * 128 + c2 * 2 + jj];
    } else if (i < 133904) {
        int j = i - 101136;                 // j = c2*256 + o*2 + jj (c2<128, o<128)
        int c2 = j >> 8, rem = j & 255, o = rem >> 1, jj = rem & 1;
        w_m1P[j] = w_m1[o * 256 + c2 * 2 + jj];
    }
}

// ---------------- main: 2 pixels per 4-wave block, 4 blocks/CU; ends at o ----------------
__global__ __launch_bounds__(256, 4) void ltae_main(
    const float* __restrict__ x,
    const float* __restrict__ b_in0, const float* __restrict__ g_in0, const float* __restrict__ be_in0,
    const float* __restrict__ b_in1, const float* __restrict__ g_in1, const float* __restrict__ be_in1,
    const float* __restrict__ g_innorm, const float* __restrict__ b_innorm,
    const _Float16* __restrict__ w1h, const _Float16* __restrict__ w1l,
    const _Float16* __restrict__ w2h, const _Float16* __restrict__ w2l,
    const _Float16* __restrict__ qkBh, const _Float16* __restrict__ qkBl,
    const float* __restrict__ qb2G, const float* __restrict__ peG,
    float* __restrict__ o_ws)
{
    __shared__ __align__(16) ushort_t Ah[48 * 128], Al[48 * 128];  // tokens, later xs2 hi/lo
    __shared__ __align__(16) ushort_t Hh[48 * 64], Hl[48 * 64];    // h1 quarter-tile hi/lo
    __shared__ float peS[24][8];
    __shared__ float2 partS[192];     // GN1 cross-wave partials [w][m][lg][r]

    float* scP = (float*)Hh;          // [2][16][24] overlays H after GEMMs (3072 B <= 6144 B)

    const int tid = threadIdx.x;
    const int bid = blockIdx.x;
    const int sb  = (bid & 7) * 576 + (bid >> 3);   // bijective XCD swizzle (4608 = 8*576)
    const int b   = sb / 1152;
    const int pixbase = (sb - b * 1152) * 2;
    const int w  = tid >> 6;
    const int l  = tid & 63;
    const int lr = l & 15;
    const int lg = l >> 4;

    // ---- Phase 0: PE cache + gather tokens -> Ah/Al (split fp16, swizzled) ----
    if (tid < 192) peS[tid >> 3][tid & 7] = peG[b * 192 + tid];
    for (int i = tid; i < 24 * 128; i += 256) {
        int t = i >> 7, c = i & 127;
        const float* gp = x + ((size_t)((b * 24 + t) * 128 + c)) * HWp + pixbase;
        float2 v = *(const float2*)gp;
        _Float16 h0 = (_Float16)v.x;
        _Float16 h1 = (_Float16)v.y;
        int i0 = sidx(t, c), i1 = sidx(24 + t, c);
        Ah[i0] = __builtin_bit_cast(ushort_t, h0);
        Al[i0] = __builtin_bit_cast(ushort_t, (_Float16)(v.x - (float)h0));
        Ah[i1] = __builtin_bit_cast(ushort_t, h1);
        Al[i1] = __builtin_bit_cast(ushort_t, (_Float16)(v.y - (float)h1));
    }
    __syncthreads();

    // ---- quarter loop: GEMM1 (64 out-ch) + GN1 + GEMM2 (64-K slice, accumulate) ----
    f32x4 acc2[3][2];
    #pragma unroll
    for (int m = 0; m < 3; m++)
        #pragma unroll
        for (int nt = 0; nt < 2; nt++) acc2[m][nt] = f32x4{0.f, 0.f, 0.f, 0.f};
    const int n2 = w * 32 + lr;           // GEMM2 out channel base (nt adds 16)

    #pragma unroll 1
    for (int q = 0; q < 4; q++) {
        // GEMM1 weights: wave owns 16 channels of this quarter
        const int n1 = q * 64 + w * 16 + lr;
        f16x8 bh[4], bl[4];
        #pragma unroll
        for (int ks = 0; ks < 4; ks++) {
            bh[ks] = *(const f16x8*)(w1h + n1 * 128 + ks * 32 + lg * 8);
            bl[ks] = *(const f16x8*)(w1l + n1 * 128 + ks * 32 + lg * 8);
        }
        const float gg = g_in0[n1], bb = be_in0[n1], bi = b_in0[n1];

        f32x4 acc1[3];
        #pragma unroll
        for (int m = 0; m < 3; m++) acc1[m] = f32x4{0.f, 0.f, 0.f, 0.f};
        #pragma unroll
        for (int m = 0; m < 3; m++) {
            #pragma unroll
            for (int ks = 0; ks < 4; ks++) {
                f16x8 ah = *(const f16x8*)&Ah[sidx(m * 16 + lr, ks * 32 + lg * 8)];
                f16x8 al = *(const f16x8*)&Al[sidx(m * 16 + lr, ks * 32 + lg * 8)];
                acc1[m] = __builtin_amdgcn_mfma_f32_16x16x32_f16(ah, bl[ks], acc1[m], 0, 0, 0);
                acc1[m] = __builtin_amdgcn_mfma_f32_16x16x32_f16(al, bh[ks], acc1[m], 0, 0, 0);
                acc1[m] = __builtin_amdgcn_mfma_f32_16x16x32_f16(ah, bh[ks], acc1[m], 0, 0, 0);
            }
        }
        // GN1 (64-ch group = all 4 waves) partials: reduce over lr lanes only
        float ps[3][4], ps2[3][4];
        #pragma unroll
        for (int m = 0; m < 3; m++) {
            #pragma unroll
            for (int r = 0; r < 4; r++) {
                float v = acc1[m][r] + bi;
                float s = v, s2 = v * v;
                #pragma unroll
                for (int mk = 1; mk <= 8; mk <<= 1) { s += __shfl_xor(s, mk); s2 += __shfl_xor(s2, mk); }
                ps[m][r] = s; ps2[m][r] = s2;
            }
        }
        if (lr == 0) {
            #pragma unroll
            for (int m = 0; m < 3; m++)
                #pragma unroll
                for (int r = 0; r < 4; r++)
                    partS[w * 48 + m * 16 + lg * 4 + r] = make_float2(ps[m][r], ps2[m][r]);
        }
        __syncthreads();
        #pragma unroll
        for (int m = 0; m < 3; m++) {
            #pragma unroll
            for (int r = 0; r < 4; r++) {
                int idx = m * 16 + lg * 4 + r;
                float st = 0.f, s2t = 0.f;
                #pragma unroll
                for (int j = 0; j < 4; j++) {
                    float2 qv = partS[j * 48 + idx];
                    st += qv.x; s2t += qv.y;
                }
                float mu = st * (1.f / 64.f);
                float rs = rsqrtf(s2t * (1.f / 64.f) - mu * mu + EPS);
                float v = acc1[m][r] + bi;
                float hv = fmaxf(fmaf((v - mu) * rs, gg, bb), 0.f);
                _Float16 h16 = (_Float16)hv;
                int ii = sidx2(idx, w * 16 + lr);
                Hh[ii] = __builtin_bit_cast(ushort_t, h16);
                Hl[ii] = __builtin_bit_cast(ushort_t, (_Float16)(hv - (float)h16));
            }
        }
        __syncthreads();

        // GEMM2 partial: K-slice = this quarter's 64 h1 channels
        f16x8 b2h[2][2], b2l[2][2];
        #pragma unroll
        for (int nt = 0; nt < 2; nt++) {
            int n = n2 + nt * 16;
            #pragma unroll
            for (int ks = 0; ks < 2; ks++) {
                b2h[nt][ks] = *(const f16x8*)(w2h + n * 256 + q * 64 + ks * 32 + lg * 8);
                b2l[nt][ks] = *(const f16x8*)(w2l + n * 256 + q * 64 + ks * 32 + lg * 8);
            }
        }
        #pragma unroll
        for (int m = 0; m < 3; m++) {
            #pragma unroll
            for (int ks = 0; ks < 2; ks++) {
                f16x8 ah = *(const f16x8*)&Hh[sidx2(m * 16 + lr, ks * 32 + lg * 8)];
                f16x8 al = *(const f16x8*)&Hl[sidx2(m * 16 + lr, ks * 32 + lg * 8)];
                #pragma unroll
                for (int nt = 0; nt < 2; nt++) {
                    acc2[m][nt] = __builtin_amdgcn_mfma_f32_16x16x32_f16(ah, b2l[nt][ks], acc2[m][nt], 0, 0, 0);
                    acc2[m][nt] = __builtin_amdgcn_mfma_f32_16x16x32_f16(al, b2h[nt][ks], acc2[m][nt], 0, 0, 0);
                    acc2[m][nt] = __builtin_amdgcn_mfma_f32_16x16x32_f16(ah, b2h[nt][ks], acc2[m][nt], 0, 0, 0);
                }
            }
        }
        __syncthreads();   // H region free for next quarter
    }

    // ---- fused epilogue: GN2 (wave-local) + in_norm (wave-local) + PE -> LDS Ah/Al ----
    {
        const int cA = w * 32 + lr;
        const int cB = cA + 16;
        float b2v[2]  = {b_in1[cA], b_in1[cB]};
        float g2v[2]  = {g_in1[cA], g_in1[cB]};
        float be2v[2] = {be_in1[cA], be_in1[cB]};
        float giV[2]  = {g_innorm[cA], g_innorm[cB]};
        float biV[2]  = {b_innorm[cA], b_innorm[cB]};

        float hv[3][4][2];
        #pragma unroll
        for (int m = 0; m < 3; m++) {
            #pragma unroll
            for (int r = 0; r < 4; r++) {
                float v0 = acc2[m][0][r] + b2v[0], v1 = acc2[m][1][r] + b2v[1];
                float s = v0 + v1, s2 = v0 * v0 + v1 * v1;
                #pragma unroll
                for (int mk = 1; mk <= 8; mk <<= 1) { s += __shfl_xor(s, mk); s2 += __shfl_xor(s2, mk); }
                float mu = s * (1.f / 32.f);
                float rs = rsqrtf(s2 * (1.f / 32.f) - mu * mu + EPS);
                hv[m][r][0] = fmaxf(fmaf((v0 - mu) * rs, g2v[0], be2v[0]), 0.f);
                hv[m][r][1] = fmaxf(fmaf((v1 - mu) * rs, g2v[1], be2v[1]), 0.f);
            }
        }
        // in_norm partials: group = 8 channels x 24 tokens of one pixel, entirely in-wave
        float s0[2] = {0.f, 0.f}, s02[2] = {0.f, 0.f};
        float s1[2] = {0.f, 0.f}, s12[2] = {0.f, 0.f};
        #pragma unroll
        for (int m = 0; m < 3; m++) {
            #pragma unroll
            for (int r = 0; r < 4; r++) {
                int row = m * 16 + lg * 4 + r;
                #pragma unroll
                for (int nt = 0; nt < 2; nt++) {
                    float v = hv[m][r][nt];
                    if (row >= 24) { s1[nt] += v; s12[nt] += v * v; }
                    else           { s0[nt] += v; s02[nt] += v * v; }
                }
            }
        }
        // reduce over lane bits 0,1,2 (channel-in-group) and 4,5 (lg): masks 1,2,4,16,32
        #pragma unroll
        for (int nt = 0; nt < 2; nt++) {
            #pragma unroll
            for (int mk = 0; mk < 5; mk++) {
                int msk = (mk < 3) ? (1 << mk) : (2 << mk);   // 1,2,4,16,32
                s0[nt] += __shfl_xor(s0[nt], msk);  s02[nt] += __shfl_xor(s02[nt], msk);
                s1[nt] += __shfl_xor(s1[nt], msk);  s12[nt] += __shfl_xor(s12[nt], msk);
            }
        }
        float mu0[2], rs0[2], mu1[2], rs1[2];
        #pragma unroll
        for (int nt = 0; nt < 2; nt++) {
            mu0[nt] = s0[nt] * (1.f / 192.f);
            rs0[nt] = rsqrtf(s02[nt] * (1.f / 192.f) - mu0[nt] * mu0[nt] + EPS);
            mu1[nt] = s1[nt] * (1.f / 192.f);
            rs1[nt] = rsqrtf(s12[nt] * (1.f / 192.f) - mu1[nt] * mu1[nt] + EPS);
        }
        // apply + PE, write xs2 hi/lo into LDS A region
        #pragma unroll
        for (int m = 0; m < 3; m++) {
            #pragma unroll
            for (int r = 0; r < 4; r++) {
                int row = m * 16 + lg * 4 + r;
                int p1 = row >= 24;
                int t = row - (p1 ? 24 : 0);
                float pe = peS[t][lr & 7];
                #pragma unroll
                for (int nt = 0; nt < 2; nt++) {
                    float mu = p1 ? mu1[nt] : mu0[nt];
                    float rs = p1 ? rs1[nt] : rs0[nt];
                    float v = fmaf((hv[m][r][nt] - mu) * rs, giV[nt], biV[nt]) + pe;
                    _Float16 h16 = (_Float16)v;
                    int ii = sidx(row, w * 32 + nt * 16 + lr);
                    Ah[ii] = __builtin_bit_cast(ushort_t, h16);
                    Al[ii] = __builtin_bit_cast(ushort_t, (_Float16)(v - (float)h16));
                }
            }
        }
    }
    __syncthreads();

    // ---- Phase 4: scores via split-fp16 MFMA (waves 0..2) ----
    if (w < 3) {
        const int m = w;
        f16x8 qh[4], ql[4];
        #pragma unroll
        for (int ks = 0; ks < 4; ks++) {
            qh[ks] = *(const f16x8*)(qkBh + ((ks * 4 + lg) * 16 + lr) * 8);
            ql[ks] = *(const f16x8*)(qkBl + ((ks * 4 + lg) * 16 + lr) * 8);
        }
        f32x4 sacc = f32x4{0.f, 0.f, 0.f, 0.f};
        #pragma unroll
        for (int ks = 0; ks < 4; ks++) {
            f16x8 ah = *(const f16x8*)&Ah[sidx(m * 16 + lr, ks * 32 + lg * 8)];
            f16x8 al = *(const f16x8*)&Al[sidx(m * 16 + lr, ks * 32 + lg * 8)];
            sacc = __builtin_amdgcn_mfma_f32_16x16x32_f16(ah, ql[ks], sacc, 0, 0, 0);
            sacc = __builtin_amdgcn_mfma_f32_16x16x32_f16(al, qh[ks], sacc, 0, 0, 0);
            sacc = __builtin_amdgcn_mfma_f32_16x16x32_f16(ah, qh[ks], sacc, 0, 0, 0);
        }
        float qb = qb2G[lr];
        #pragma unroll
        for (int r = 0; r < 4; r++) {
            int row = m * 16 + lg * 4 + r;
            int p = row >= 24 ? 1 : 0;
            int t = row - p * 24;
            scP[(p * 16 + lr) * 24 + t] = sacc[r] + qb;
        }
    }
    __syncthreads();

    // ---- softmax: wave w -> pixel w>>1, heads (w&1)*8 + l>>3 ----
    {
        const int p = w >> 1;
        int h = (w & 1) * 8 + (l >> 3), j = l & 7;
        float* sp = scP + (p * 16 + h) * 24;
        float mx = -1e30f;
        #pragma unroll
        for (int k = 0; k < 3; k++) mx = fmaxf(mx, sp[j + 8 * k]);
        mx = fmaxf(mx, __shfl_xor(mx, 1));
        mx = fmaxf(mx, __shfl_xor(mx, 2));
        mx = fmaxf(mx, __shfl_xor(mx, 4));
        float ev[3], sum = 0.f;
        #pragma unroll
        for (int k = 0; k < 3; k++) { ev[k] = __expf(sp[j + 8 * k] - mx); sum += ev[k]; }
        sum += __shfl_xor(sum, 1);
        sum += __shfl_xor(sum, 2);
        sum += __shfl_xor(sum, 4);
        float inv = 1.f / sum;
        #pragma unroll
        for (int k = 0; k < 3; k++) sp[j + 8 * k] = ev[k] * inv;
    }

    // ---- Phase 5: o = a . v -> global o_ws; kernel A ends here ----
    {
        const int p = w >> 1;
        int ch = (w & 1) * 64 + l;
        int h = ch >> 3;
        const float* sp = scP + (p * 16 + h) * 24;
        float s = 0.f;
        #pragma unroll
        for (int t = 0; t < 24; t++) {
            int ii = sidx(p * 24 + t, ch);
            float v = (float)__builtin_bit_cast(_Float16, Ah[ii]) +
                      (float)__builtin_bit_cast(_Float16, Al[ii]);
            s = fmaf(sp[t], v, s);
        }
        o_ws[((size_t)(b * 2304 + pixbase + p)) * 128 + ch] = s;
    }
}

// ---------------- mlp: output MLP + norms, 8 pixels per 256-thread block ----------------
__global__ __launch_bounds__(256) void ltae_mlp(
    const float* __restrict__ o_ws,
    const float* __restrict__ w_m0P, const float* __restrict__ b_m0,
    const float* __restrict__ g_m0, const float* __restrict__ be_m0,
    const float* __restrict__ w_m1P, const float* __restrict__ b_m1,
    const float* __restrict__ g_m1, const float* __restrict__ be_m1,
    const float* __restrict__ g_out, const float* __restrict__ b_out,
    float* __restrict__ out)
{
    __shared__ float ovP[8 * 128];    // later reused as ysP
    __shared__ float mmP[8 * 256];
    float* ysP = ovP;

    const int tid = threadIdx.x;
    const int bid = blockIdx.x;       // 1152 = 4 b * 288
    const int b = bid / 288;
    const int pix8 = (bid - b * 288) * 8;

    // load o for 8 pixels (coalesced)
    #pragma unroll
    for (int k = 0; k < 4; k++) {
        int i = tid + (k << 8);       // 0..1023
        ovP[i] = o_ws[((size_t)(b * 2304 + pix8)) * 128 + i];
    }
    __syncthreads();

    // MLP layer 1 (128->256) + GN(4/64) + ReLU, 8 pixels; coalesced paired weights
    {
        const int o = tid;
        float acc[8];
        #pragma unroll
        for (int pp = 0; pp < 8; pp++) acc[pp] = 0.f;
        for (int c2 = 0; c2 < 64; c2++) {
            float2 w2 = *(const float2*)(w_m0P + c2 * 512 + o * 2);
            #pragma unroll
            for (int pp = 0; pp < 8; pp++) {
                float2 x2 = *(const float2*)(ovP + pp * 128 + c2 * 2);
                acc[pp] = fmaf(w2.x, x2.x, acc[pp]);
                acc[pp] = fmaf(w2.y, x2.y, acc[pp]);
            }
        }
        float bi = b_m0[o], gg = g_m0[o], bb = be_m0[o];
        #pragma unroll
        for (int pp = 0; pp < 8; pp++) {
            float v = acc[pp] + bi;
            float s = v, s2 = v * v;
            #pragma unroll
            for (int mk = 1; mk <= 32; mk <<= 1) { s += __shfl_xor(s, mk); s2 += __shfl_xor(s2, mk); }
            float mu = s * (1.f / 64.f);
            float rs = rsqrtf(s2 * (1.f / 64.f) - mu * mu + EPS);
            mmP[pp * 256 + o] = fmaxf(fmaf((v - mu) * rs, gg, bb), 0.f);
        }
    }
    __syncthreads();

    // MLP layer 2 (256->128) + GN(4/32) + ReLU + out_norm GN(16/8); coalesced paired weights
    {
        const int o = tid & 127, hw = tid >> 7;
        float acc[4];
        #pragma unroll
        for (int q = 0; q < 4; q++) acc[q] = 0.f;
        for (int c2 = 0; c2 < 128; c2++) {
            float2 w2 = *(const float2*)(w_m1P + c2 * 256 + o * 2);
            #pragma unroll
            for (int q = 0; q < 4; q++) {
                float2 x2 = *(const float2*)(mmP + (hw * 4 + q) * 256 + c2 * 2);
                acc[q] = fmaf(w2.x, x2.x, acc[q]);
                acc[q] = fmaf(w2.y, x2.y, acc[q]);
            }
        }
        float bm1 = b_m1[o], gm1 = g_m1[o], bem1 = be_m1[o];
        float go = g_out[o], bo = b_out[o];
        #pragma unroll
        for (int q = 0; q < 4; q++) {
            const int pp = hw * 4 + q;
            float v = acc[q] + bm1;
            float s = v, s2 = v * v;
            #pragma unroll
            for (int mk = 1; mk <= 16; mk <<= 1) { s += __shfl_xor(s, mk); s2 += __shfl_xor(s2, mk); }
            float mu = s * (1.f / 32.f);
            float rs = rsqrtf(s2 * (1.f / 32.f) - mu * mu + EPS);
            float v2 = fmaxf(fmaf((v - mu) * rs, gm1, bem1), 0.f);
            float t1 = v2, t2 = v2 * v2;
            #pragma unroll
            for (int mk = 1; mk <= 4; mk <<= 1) { t1 += __shfl_xor(t1, mk); t2 += __shfl_xor(t2, mk); }
            float mu2 = t1 * (1.f / 8.f);
            float rs2 = rsqrtf(t2 * (1.f / 8.f) - mu2 * mu2 + EPS);
            ysP[pp * 128 + o] = fmaf((v2 - mu2) * rs2, go, bo);
        }
    }
    __syncthreads();

    // store: float4 across 4 consecutive pixels
    {
        const int o = tid & 127, q4 = (tid >> 7) * 4;
        float4 y4;
        y4.x = ysP[(q4 + 0) * 128 + o];
        y4.y = ysP[(q4 + 1) * 128 + o];
        y4.z = ysP[(q4 + 2) * 128 + o];
        y4.w = ysP[(q4 + 3) * 128 + o];
        *(float4*)(out + ((size_t)(b * 128 + o)) * HWp + pix8 + q4) = y4;
    }
}

extern "C" void kernel_launch(void* const* d_in, const int* in_sizes, int n_in,
                              void* d_out, int out_size, void* d_ws, size_t ws_size,
                              hipStream_t stream) {
    const float* x        = (const float*)d_in[0];
    const int*   bpos     = (const int*)  d_in[1];
    const float* w_in0    = (const float*)d_in[2];
    const float* b_in0    = (const float*)d_in[3];
    const float* g_in0    = (const float*)d_in[4];
    const float* be_in0   = (const float*)d_in[5];
    const float* w_in1    = (const float*)d_in[6];
    const float* b_in1    = (const float*)d_in[7];
    const float* g_in1    = (const float*)d_in[8];
    const float* be_in1   = (const float*)d_in[9];
    const float* g_innorm = (const float*)d_in[10];
    const float* b_innorm = (const float*)d_in[11];
    const float* Qm       = (const float*)d_in[12];
    const float* w_k      = (const float*)d_in[13];
    const float* b_k      = (const float*)d_in[14];
    const float* w_m0     = (const float*)d_in[15];
    const float* b_m0     = (const float*)d_in[16];
    const float* g_m0     = (const float*)d_in[17];
    const float* be_m0    = (const float*)d_in[18];
    const float* w_m1     = (const float*)d_in[19];
    const float* b_m1     = (const float*)d_in[20];
    const float* g_m1     = (const float*)d_in[21];
    const float* be_m1    = (const float*)d_in[22];
    const float* g_out    = (const float*)d_in[23];
    const float* b_out    = (const float*)d_in[24];

    _Float16* w1h   = (_Float16*)d_ws;
    _Float16* w1l   = w1h + 32768;
    _Float16* w2h   = w1l + 32768;
    _Float16* w2l   = w2h + 32768;
    _Float16* qkBh  = (_Float16*)((char*)d_ws + 262144);
    _Float16* qkBl  = qkBh + 2048;
    float*    qb2G  = (float*)((char*)d_ws + 270336);
    float*    peG   = (float*)((char*)d_ws + 270400);
    float*    w_m0P = (float*)((char*)d_ws + M0P_OFF);
    float*    w_m1P = (float*)((char*)d_ws + M1P_OFF);
    float*    o_ws  = (float*)((char*)d_ws + OWS_OFF);

    hipLaunchKernelGGL(ltae_prep, dim3(524), dim3(256), 0, stream,
                       w_in0, w_in1, Qm, w_k, b_k, bpos, w_m0, w_m1,
                       w1h, w1l, w2h, w2l, qkBh, qkBl, qb2G, peG, w_m0P, w_m1P);

    hipLaunchKernelGGL(ltae_main, dim3(4608), dim3(256), 0, stream,
                       x,
                       b_in0, g_in0, be_in0,
                       b_in1, g_in1, be_in1,
                       g_innorm, b_innorm,
                       w1h, w1l, w2h, w2l, qkBh, qkBl, qb2G, peG,
                       o_ws);

    hipLaunchKernelGGL(ltae_mlp, dim3(1152), dim3(256), 0, stream,
                       o_ws,
                       w_m0P, b_m0, g_m0, be_m0,
                       w_m1P, b_m1, g_m1, be_m1,
                       g_out, b_out,
                       (float*)d_out);
}

// Round 15
// 309.295 us; speedup vs baseline: 1.1379x; 1.1379x over previous
//
#include <hip/hip_runtime.h>
#include <math.h>

typedef _Float16 f16x8 __attribute__((ext_vector_type(8)));
typedef float f32x4 __attribute__((ext_vector_type(4)));
typedef unsigned short ushort_t;

constexpr int HWp = 2304;
constexpr float EPS = 1e-5f;

// ws layout (bytes): w1h@0, w1l@65536, w2h@131072, w2l@196608 (fp16, 32768 each)
//   qkBh@262144 (4096), qkBl@266240 (4096), qb2@270336 (64), peG@270400 (3072)
//   w_m0P@273472 (131072), w_m1P@404544 (131072), o_ws@535616 (4718592)
constexpr size_t M0P_OFF = 273472;
constexpr size_t M1P_OFF = 404544;
constexpr size_t OWS_OFF = 535616;

// swizzled ushort index, 256B rows (128 fp16 cols): byte = row*256 + ((c*2)^((row&7)<<4))
__device__ __forceinline__ int sidx(int row, int c) {
    return ((row << 8) + ((c << 1) ^ ((row & 7) << 4))) >> 1;
}
// swizzled ushort index, 128B rows (64 fp16 cols)
__device__ __forceinline__ int sidx2(int row, int c) {
    return ((row << 7) + ((c << 1) ^ ((row & 7) << 4))) >> 1;
}

// ---------------- prep: weights -> split fp16, fold Q+scale, PE table, mlp weight transpose ----------------
__global__ void ltae_prep(const float* __restrict__ w_in0, const float* __restrict__ w_in1,
                          const float* __restrict__ Qm, const float* __restrict__ w_k,
                          const float* __restrict__ b_k, const int* __restrict__ bpos,
                          const float* __restrict__ w_m0, const float* __restrict__ w_m1,
                          _Float16* __restrict__ w1h, _Float16* __restrict__ w1l,
                          _Float16* __restrict__ w2h, _Float16* __restrict__ w2l,
                          _Float16* __restrict__ qkBh, _Float16* __restrict__ qkBl,
                          float* __restrict__ qb2G, float* __restrict__ peG,
                          float* __restrict__ w_m0P, float* __restrict__ w_m1P) {
    int i = blockIdx.x * 256 + threadIdx.x;
    if (i < 32768) {
        float v = w_in0[i];
        _Float16 h = (_Float16)v;
        w1h[i] = h; w1l[i] = (_Float16)(v - (float)h);
    } else if (i < 65536) {
        int j = i - 32768;
        float v = w_in1[j];
        _Float16 h = (_Float16)v;
        w2h[j] = h; w2l[j] = (_Float16)(v - (float)h);
    } else if (i < 67584) {
        int j = i - 65536; int h = j >> 7, k = j & 127;
        float s = 0.f;
        #pragma unroll
        for (int dk = 0; dk < 4; dk++) s = fmaf(Qm[h * 4 + dk], w_k[(h * 4 + dk) * 128 + k], s);
        s *= 0.5f;
        _Float16 hi = (_Float16)s;
        int ks = k >> 5, lg = (k >> 3) & 3, jj = k & 7;
        int pos = ((ks * 4 + lg) * 16 + h) * 8 + jj;
        qkBh[pos] = hi; qkBl[pos] = (_Float16)(s - (float)hi);
    } else if (i < 67600) {
        int h = i - 67584;
        float s = 0.f;
        #pragma unroll
        for (int dk = 0; dk < 4; dk++) s = fmaf(Qm[h * 4 + dk], b_k[h * 4 + dk], s);
        qb2G[h] = 0.5f * s;
    } else if (i < 68368) {
        int j = i - 67600;
        int bb = j / 192, r = j - bb * 192;
        int t = r >> 3, d = r & 7;
        const float dens[4] = {1.0f, 5.623413251903491f, 31.622776601683793f, 177.82794100389228f};
        float ang = (float)bpos[bb * 24 + t] / dens[d >> 1];
        peG[j] = (d & 1) ? cosf(ang) : sinf(ang);
    } else if (i < 101136) {
        int j = i - 68368;                  // j = c2*512 + o*2 + jj (c2<64, o<256)
        int c2 = j >> 9, rem = j & 511, o = rem >> 1, jj = rem & 1;
        w_m0P[j] = w_m0[o * 128 + c2 * 2 + jj];
    } else if (i < 133904) {
        int j = i - 101136;                 // j = c2*256 + o*2 + jj (c2<128, o<128)
        int c2 = j >> 8, rem = j & 255, o = rem >> 1, jj = rem & 1;
        w_m1P[j] = w_m1[o * 256 + c2 * 2 + jj];
    }
}

// ---------------- main: 2 pixels per 4-wave block, LDS 39.4KB -> 4 blocks/CU; ends at o ----------------
__global__ __launch_bounds__(256, 3) void ltae_main(
    const float* __restrict__ x,
    const float* __restrict__ b_in0, const float* __restrict__ g_in0, const float* __restrict__ be_in0,
    const float* __restrict__ b_in1, const float* __restrict__ g_in1, const float* __restrict__ be_in1,
    const float* __restrict__ g_innorm, const float* __restrict__ b_innorm,
    const _Float16* __restrict__ w1h, const _Float16* __restrict__ w1l,
    const _Float16* __restrict__ w2h, const _Float16* __restrict__ w2l,
    const _Float16* __restrict__ qkBh, const _Float16* __restrict__ qkBl,
    const float* __restrict__ qb2G, const float* __restrict__ peG,
    float* __restrict__ o_ws)
{
    __shared__ __align__(16) ushort_t Ah[48 * 128], Al[48 * 128];  // tokens, later xs2 hi/lo
    __shared__ __align__(16) ushort_t Hh[48 * 64], Hl[48 * 64];    // h1 quarter-tile hi/lo
    __shared__ float peS[24][8];
    __shared__ float2 partS[192];     // GN1 cross-wave partials [w][m][lg][r]

    float* scP = (float*)Hh;          // [2][16][24] overlays H after GEMMs (3072 B <= 6144 B)

    const int tid = threadIdx.x;
    const int bid = blockIdx.x;
    const int sb  = (bid & 7) * 576 + (bid >> 3);   // bijective XCD swizzle (4608 = 8*576)
    const int b   = sb / 1152;
    const int pixbase = (sb - b * 1152) * 2;
    const int w  = tid >> 6;
    const int l  = tid & 63;
    const int lr = l & 15;
    const int lg = l >> 4;

    // ---- Phase 0: PE cache + gather tokens -> Ah/Al (split fp16, swizzled) ----
    if (tid < 192) peS[tid >> 3][tid & 7] = peG[b * 192 + tid];
    for (int i = tid; i < 24 * 128; i += 256) {
        int t = i >> 7, c = i & 127;
        const float* gp = x + ((size_t)((b * 24 + t) * 128 + c)) * HWp + pixbase;
        float2 v = *(const float2*)gp;
        _Float16 h0 = (_Float16)v.x;
        _Float16 h1 = (_Float16)v.y;
        int i0 = sidx(t, c), i1 = sidx(24 + t, c);
        Ah[i0] = __builtin_bit_cast(ushort_t, h0);
        Al[i0] = __builtin_bit_cast(ushort_t, (_Float16)(v.x - (float)h0));
        Ah[i1] = __builtin_bit_cast(ushort_t, h1);
        Al[i1] = __builtin_bit_cast(ushort_t, (_Float16)(v.y - (float)h1));
    }
    __syncthreads();

    // ---- quarter loop: GEMM1 (64 out-ch) + GN1 + GEMM2 (64-K slice, accumulate) ----
    f32x4 acc2[3][2];
    #pragma unroll
    for (int m = 0; m < 3; m++)
        #pragma unroll
        for (int nt = 0; nt < 2; nt++) acc2[m][nt] = f32x4{0.f, 0.f, 0.f, 0.f};
    const int n2 = w * 32 + lr;           // GEMM2 out channel base (nt adds 16)

    #pragma unroll 1
    for (int q = 0; q < 4; q++) {
        // GEMM1 weights: wave owns 16 channels of this quarter
        const int n1 = q * 64 + w * 16 + lr;
        f16x8 bh[4], bl[4];
        #pragma unroll
        for (int ks = 0; ks < 4; ks++) {
            bh[ks] = *(const f16x8*)(w1h + n1 * 128 + ks * 32 + lg * 8);
            bl[ks] = *(const f16x8*)(w1l + n1 * 128 + ks * 32 + lg * 8);
        }
        const float gg = g_in0[n1], bb = be_in0[n1], bi = b_in0[n1];

        f32x4 acc1[3];
        #pragma unroll
        for (int m = 0; m < 3; m++) acc1[m] = f32x4{0.f, 0.f, 0.f, 0.f};
        #pragma unroll
        for (int m = 0; m < 3; m++) {
            #pragma unroll
            for (int ks = 0; ks < 4; ks++) {
                f16x8 ah = *(const f16x8*)&Ah[sidx(m * 16 + lr, ks * 32 + lg * 8)];
                f16x8 al = *(const f16x8*)&Al[sidx(m * 16 + lr, ks * 32 + lg * 8)];
                acc1[m] = __builtin_amdgcn_mfma_f32_16x16x32_f16(ah, bl[ks], acc1[m], 0, 0, 0);
                acc1[m] = __builtin_amdgcn_mfma_f32_16x16x32_f16(al, bh[ks], acc1[m], 0, 0, 0);
                acc1[m] = __builtin_amdgcn_mfma_f32_16x16x32_f16(ah, bh[ks], acc1[m], 0, 0, 0);
            }
        }
        // GN1 (64-ch group = all 4 waves) partials: reduce over lr lanes only
        float ps[3][4], ps2[3][4];
        #pragma unroll
        for (int m = 0; m < 3; m++) {
            #pragma unroll
            for (int r = 0; r < 4; r++) {
                float v = acc1[m][r] + bi;
                float s = v, s2 = v * v;
                #pragma unroll
                for (int mk = 1; mk <= 8; mk <<= 1) { s += __shfl_xor(s, mk); s2 += __shfl_xor(s2, mk); }
                ps[m][r] = s; ps2[m][r] = s2;
            }
        }
        if (lr == 0) {
            #pragma unroll
            for (int m = 0; m < 3; m++)
                #pragma unroll
                for (int r = 0; r < 4; r++)
                    partS[w * 48 + m * 16 + lg * 4 + r] = make_float2(ps[m][r], ps2[m][r]);
        }
        __syncthreads();
        #pragma unroll
        for (int m = 0; m < 3; m++) {
            #pragma unroll
            for (int r = 0; r < 4; r++) {
                int idx = m * 16 + lg * 4 + r;
                float st = 0.f, s2t = 0.f;
                #pragma unroll
                for (int j = 0; j < 4; j++) {
                    float2 qv = partS[j * 48 + idx];
                    st += qv.x; s2t += qv.y;
                }
                float mu = st * (1.f / 64.f);
                float rs = rsqrtf(s2t * (1.f / 64.f) - mu * mu + EPS);
                float v = acc1[m][r] + bi;
                float hv = fmaxf(fmaf((v - mu) * rs, gg, bb), 0.f);
                _Float16 h16 = (_Float16)hv;
                int ii = sidx2(idx, w * 16 + lr);
                Hh[ii] = __builtin_bit_cast(ushort_t, h16);
                Hl[ii] = __builtin_bit_cast(ushort_t, (_Float16)(hv - (float)h16));
            }
        }
        __syncthreads();

        // GEMM2 partial: K-slice = this quarter's 64 h1 channels
        f16x8 b2h[2][2], b2l[2][2];
        #pragma unroll
        for (int nt = 0; nt < 2; nt++) {
            int n = n2 + nt * 16;
            #pragma unroll
            for (int ks = 0; ks < 2; ks++) {
                b2h[nt][ks] = *(const f16x8*)(w2h + n * 256 + q * 64 + ks * 32 + lg * 8);
                b2l[nt][ks] = *(const f16x8*)(w2l + n * 256 + q * 64 + ks * 32 + lg * 8);
            }
        }
        #pragma unroll
        for (int m = 0; m < 3; m++) {
            #pragma unroll
            for (int ks = 0; ks < 2; ks++) {
                f16x8 ah = *(const f16x8*)&Hh[sidx2(m * 16 + lr, ks * 32 + lg * 8)];
                f16x8 al = *(const f16x8*)&Hl[sidx2(m * 16 + lr, ks * 32 + lg * 8)];
                #pragma unroll
                for (int nt = 0; nt < 2; nt++) {
                    acc2[m][nt] = __builtin_amdgcn_mfma_f32_16x16x32_f16(ah, b2l[nt][ks], acc2[m][nt], 0, 0, 0);
                    acc2[m][nt] = __builtin_amdgcn_mfma_f32_16x16x32_f16(al, b2h[nt][ks], acc2[m][nt], 0, 0, 0);
                    acc2[m][nt] = __builtin_amdgcn_mfma_f32_16x16x32_f16(ah, b2h[nt][ks], acc2[m][nt], 0, 0, 0);
                }
            }
        }
        __syncthreads();   // H region free for next quarter
    }

    // ---- fused epilogue: GN2 (wave-local) + in_norm (wave-local) + PE -> LDS Ah/Al ----
    {
        const int cA = w * 32 + lr;
        const int cB = cA + 16;
        float b2v[2]  = {b_in1[cA], b_in1[cB]};
        float g2v[2]  = {g_in1[cA], g_in1[cB]};
        float be2v[2] = {be_in1[cA], be_in1[cB]};
        float giV[2]  = {g_innorm[cA], g_innorm[cB]};
        float biV[2]  = {b_innorm[cA], b_innorm[cB]};

        float hv[3][4][2];
        #pragma unroll
        for (int m = 0; m < 3; m++) {
            #pragma unroll
            for (int r = 0; r < 4; r++) {
                float v0 = acc2[m][0][r] + b2v[0], v1 = acc2[m][1][r] + b2v[1];
                float s = v0 + v1, s2 = v0 * v0 + v1 * v1;
                #pragma unroll
                for (int mk = 1; mk <= 8; mk <<= 1) { s += __shfl_xor(s, mk); s2 += __shfl_xor(s2, mk); }
                float mu = s * (1.f / 32.f);
                float rs = rsqrtf(s2 * (1.f / 32.f) - mu * mu + EPS);
                hv[m][r][0] = fmaxf(fmaf((v0 - mu) * rs, g2v[0], be2v[0]), 0.f);
                hv[m][r][1] = fmaxf(fmaf((v1 - mu) * rs, g2v[1], be2v[1]), 0.f);
            }
        }
        // in_norm partials: group = 8 channels x 24 tokens of one pixel, entirely in-wave
        float s0[2] = {0.f, 0.f}, s02[2] = {0.f, 0.f};
        float s1[2] = {0.f, 0.f}, s12[2] = {0.f, 0.f};
        #pragma unroll
        for (int m = 0; m < 3; m++) {
            #pragma unroll
            for (int r = 0; r < 4; r++) {
                int row = m * 16 + lg * 4 + r;
                #pragma unroll
                for (int nt = 0; nt < 2; nt++) {
                    float v = hv[m][r][nt];
                    if (row >= 24) { s1[nt] += v; s12[nt] += v * v; }
                    else           { s0[nt] += v; s02[nt] += v * v; }
                }
            }
        }
        // reduce over lane bits 0,1,2 (channel-in-group) and 4,5 (lg): masks 1,2,4,16,32
        #pragma unroll
        for (int nt = 0; nt < 2; nt++) {
            #pragma unroll
            for (int mk = 0; mk < 5; mk++) {
                int msk = (mk < 3) ? (1 << mk) : (2 << mk);   // 1,2,4,16,32
                s0[nt] += __shfl_xor(s0[nt], msk);  s02[nt] += __shfl_xor(s02[nt], msk);
                s1[nt] += __shfl_xor(s1[nt], msk);  s12[nt] += __shfl_xor(s12[nt], msk);
            }
        }
        float mu0[2], rs0[2], mu1[2], rs1[2];
        #pragma unroll
        for (int nt = 0; nt < 2; nt++) {
            mu0[nt] = s0[nt] * (1.f / 192.f);
            rs0[nt] = rsqrtf(s02[nt] * (1.f / 192.f) - mu0[nt] * mu0[nt] + EPS);
            mu1[nt] = s1[nt] * (1.f / 192.f);
            rs1[nt] = rsqrtf(s12[nt] * (1.f / 192.f) - mu1[nt] * mu1[nt] + EPS);
        }
        // apply + PE, write xs2 hi/lo into LDS A region
        #pragma unroll
        for (int m = 0; m < 3; m++) {
            #pragma unroll
            for (int r = 0; r < 4; r++) {
                int row = m * 16 + lg * 4 + r;
                int p1 = row >= 24;
                int t = row - (p1 ? 24 : 0);
                float pe = peS[t][lr & 7];
                #pragma unroll
                for (int nt = 0; nt < 2; nt++) {
                    float mu = p1 ? mu1[nt] : mu0[nt];
                    float rs = p1 ? rs1[nt] : rs0[nt];
                    float v = fmaf((hv[m][r][nt] - mu) * rs, giV[nt], biV[nt]) + pe;
                    _Float16 h16 = (_Float16)v;
                    int ii = sidx(row, w * 32 + nt * 16 + lr);
                    Ah[ii] = __builtin_bit_cast(ushort_t, h16);
                    Al[ii] = __builtin_bit_cast(ushort_t, (_Float16)(v - (float)h16));
                }
            }
        }
    }
    __syncthreads();

    // ---- Phase 4: scores via split-fp16 MFMA (waves 0..2) ----
    if (w < 3) {
        const int m = w;
        f16x8 qh[4], ql[4];
        #pragma unroll
        for (int ks = 0; ks < 4; ks++) {
            qh[ks] = *(const f16x8*)(qkBh + ((ks * 4 + lg) * 16 + lr) * 8);
            ql[ks] = *(const f16x8*)(qkBl + ((ks * 4 + lg) * 16 + lr) * 8);
        }
        f32x4 sacc = f32x4{0.f, 0.f, 0.f, 0.f};
        #pragma unroll
        for (int ks = 0; ks < 4; ks++) {
            f16x8 ah = *(const f16x8*)&Ah[sidx(m * 16 + lr, ks * 32 + lg * 8)];
            f16x8 al = *(const f16x8*)&Al[sidx(m * 16 + lr, ks * 32 + lg * 8)];
            sacc = __builtin_amdgcn_mfma_f32_16x16x32_f16(ah, ql[ks], sacc, 0, 0, 0);
            sacc = __builtin_amdgcn_mfma_f32_16x16x32_f16(al, qh[ks], sacc, 0, 0, 0);
            sacc = __builtin_amdgcn_mfma_f32_16x16x32_f16(ah, qh[ks], sacc, 0, 0, 0);
        }
        float qb = qb2G[lr];
        #pragma unroll
        for (int r = 0; r < 4; r++) {
            int row = m * 16 + lg * 4 + r;
            int p = row >= 24 ? 1 : 0;
            int t = row - p * 24;
            scP[(p * 16 + lr) * 24 + t] = sacc[r] + qb;
        }
    }
    __syncthreads();

    // ---- softmax: wave w -> pixel w>>1, heads (w&1)*8 + l>>3 ----
    {
        const int p = w >> 1;
        int h = (w & 1) * 8 + (l >> 3), j = l & 7;
        float* sp = scP + (p * 16 + h) * 24;
        float mx = -1e30f;
        #pragma unroll
        for (int k = 0; k < 3; k++) mx = fmaxf(mx, sp[j + 8 * k]);
        mx = fmaxf(mx, __shfl_xor(mx, 1));
        mx = fmaxf(mx, __shfl_xor(mx, 2));
        mx = fmaxf(mx, __shfl_xor(mx, 4));
        float ev[3], sum = 0.f;
        #pragma unroll
        for (int k = 0; k < 3; k++) { ev[k] = __expf(sp[j + 8 * k] - mx); sum += ev[k]; }
        sum += __shfl_xor(sum, 1);
        sum += __shfl_xor(sum, 2);
        sum += __shfl_xor(sum, 4);
        float inv = 1.f / sum;
        #pragma unroll
        for (int k = 0; k < 3; k++) sp[j + 8 * k] = ev[k] * inv;
    }

    // ---- Phase 5: o = a . v -> global o_ws; kernel A ends here ----
    {
        const int p = w >> 1;
        int ch = (w & 1) * 64 + l;
        int h = ch >> 3;
        const float* sp = scP + (p * 16 + h) * 24;
        float s = 0.f;
        #pragma unroll
        for (int t = 0; t < 24; t++) {
            int ii = sidx(p * 24 + t, ch);
            float v = (float)__builtin_bit_cast(_Float16, Ah[ii]) +
                      (float)__builtin_bit_cast(_Float16, Al[ii]);
            s = fmaf(sp[t], v, s);
        }
        o_ws[((size_t)(b * 2304 + pixbase + p)) * 128 + ch] = s;
    }
}

// ---------------- mlp: output MLP + norms, 8 pixels per 256-thread block ----------------
__global__ __launch_bounds__(256) void ltae_mlp(
    const float* __restrict__ o_ws,
    const float* __restrict__ w_m0P, const float* __restrict__ b_m0,
    const float* __restrict__ g_m0, const float* __restrict__ be_m0,
    const float* __restrict__ w_m1P, const float* __restrict__ b_m1,
    const float* __restrict__ g_m1, const float* __restrict__ be_m1,
    const float* __restrict__ g_out, const float* __restrict__ b_out,
    float* __restrict__ out)
{
    __shared__ float ovP[8 * 128];    // later reused as ysP
    __shared__ float mmP[8 * 256];
    float* ysP = ovP;

    const int tid = threadIdx.x;
    const int bid = blockIdx.x;       // 1152 = 4 b * 288
    const int b = bid / 288;
    const int pix8 = (bid - b * 288) * 8;

    // load o for 8 pixels (coalesced)
    #pragma unroll
    for (int k = 0; k < 4; k++) {
        int i = tid + (k << 8);       // 0..1023
        ovP[i] = o_ws[((size_t)(b * 2304 + pix8)) * 128 + i];
    }
    __syncthreads();

    // MLP layer 1 (128->256) + GN(4/64) + ReLU, 8 pixels; coalesced paired weights
    {
        const int o = tid;
        float acc[8];
        #pragma unroll
        for (int pp = 0; pp < 8; pp++) acc[pp] = 0.f;
        for (int c2 = 0; c2 < 64; c2++) {
            float2 w2 = *(const float2*)(w_m0P + c2 * 512 + o * 2);
            #pragma unroll
            for (int pp = 0; pp < 8; pp++) {
                float2 x2 = *(const float2*)(ovP + pp * 128 + c2 * 2);
                acc[pp] = fmaf(w2.x, x2.x, acc[pp]);
                acc[pp] = fmaf(w2.y, x2.y, acc[pp]);
            }
        }
        float bi = b_m0[o], gg = g_m0[o], bb = be_m0[o];
        #pragma unroll
        for (int pp = 0; pp < 8; pp++) {
            float v = acc[pp] + bi;
            float s = v, s2 = v * v;
            #pragma unroll
            for (int mk = 1; mk <= 32; mk <<= 1) { s += __shfl_xor(s, mk); s2 += __shfl_xor(s2, mk); }
            float mu = s * (1.f / 64.f);
            float rs = rsqrtf(s2 * (1.f / 64.f) - mu * mu + EPS);
            mmP[pp * 256 + o] = fmaxf(fmaf((v - mu) * rs, gg, bb), 0.f);
        }
    }
    __syncthreads();

    // MLP layer 2 (256->128) + GN(4/32) + ReLU + out_norm GN(16/8); coalesced paired weights
    {
        const int o = tid & 127, hw = tid >> 7;
        float acc[4];
        #pragma unroll
        for (int q = 0; q < 4; q++) acc[q] = 0.f;
        for (int c2 = 0; c2 < 128; c2++) {
            float2 w2 = *(const float2*)(w_m1P + c2 * 256 + o * 2);
            #pragma unroll
            for (int q = 0; q < 4; q++) {
                float2 x2 = *(const float2*)(mmP + (hw * 4 + q) * 256 + c2 * 2);
                acc[q] = fmaf(w2.x, x2.x, acc[q]);
                acc[q] = fmaf(w2.y, x2.y, acc[q]);
            }
        }
        float bm1 = b_m1[o], gm1 = g_m1[o], bem1 = be_m1[o];
        float go = g_out[o], bo = b_out[o];
        #pragma unroll
        for (int q = 0; q < 4; q++) {
            const int pp = hw * 4 + q;
            float v = acc[q] + bm1;
            float s = v, s2 = v * v;
            #pragma unroll
            for (int mk = 1; mk <= 16; mk <<= 1) { s += __shfl_xor(s, mk); s2 += __shfl_xor(s2, mk); }
            float mu = s * (1.f / 32.f);
            float rs = rsqrtf(s2 * (1.f / 32.f) - mu * mu + EPS);
            float v2 = fmaxf(fmaf((v - mu) * rs, gm1, bem1), 0.f);
            float t1 = v2, t2 = v2 * v2;
            #pragma unroll
            for (int mk = 1; mk <= 4; mk <<= 1) { t1 += __shfl_xor(t1, mk); t2 += __shfl_xor(t2, mk); }
            float mu2 = t1 * (1.f / 8.f);
            float rs2 = rsqrtf(t2 * (1.f / 8.f) - mu2 * mu2 + EPS);
            ysP[pp * 128 + o] = fmaf((v2 - mu2) * rs2, go, bo);
        }
    }
    __syncthreads();

    // store: float4 across 4 consecutive pixels
    {
        const int o = tid & 127, q4 = (tid >> 7) * 4;
        float4 y4;
        y4.x = ysP[(q4 + 0) * 128 + o];
        y4.y = ysP[(q4 + 1) * 128 + o];
        y4.z = ysP[(q4 + 2) * 128 + o];
        y4.w = ysP[(q4 + 3) * 128 + o];
        *(float4*)(out + ((size_t)(b * 128 + o)) * HWp + pix8 + q4) = y4;
    }
}

extern "C" void kernel_launch(void* const* d_in, const int* in_sizes, int n_in,
                              void* d_out, int out_size, void* d_ws, size_t ws_size,
                              hipStream_t stream) {
    const float* x        = (const float*)d_in[0];
    const int*   bpos     = (const int*)  d_in[1];
    const float* w_in0    = (const float*)d_in[2];
    const float* b_in0    = (const float*)d_in[3];
    const float* g_in0    = (const float*)d_in[4];
    const float* be_in0   = (const float*)d_in[5];
    const float* w_in1    = (const float*)d_in[6];
    const float* b_in1    = (const float*)d_in[7];
    const float* g_in1    = (const float*)d_in[8];
    const float* be_in1   = (const float*)d_in[9];
    const float* g_innorm = (const float*)d_in[10];
    const float* b_innorm = (const float*)d_in[11];
    const float* Qm       = (const float*)d_in[12];
    const float* w_k      = (const float*)d_in[13];
    const float* b_k      = (const float*)d_in[14];
    const float* w_m0     = (const float*)d_in[15];
    const float* b_m0     = (const float*)d_in[16];
    const float* g_m0     = (const float*)d_in[17];
    const float* be_m0    = (const float*)d_in[18];
    const float* w_m1     = (const float*)d_in[19];
    const float* b_m1     = (const float*)d_in[20];
    const float* g_m1     = (const float*)d_in[21];
    const float* be_m1    = (const float*)d_in[22];
    const float* g_out    = (const float*)d_in[23];
    const float* b_out    = (const float*)d_in[24];

    _Float16* w1h   = (_Float16*)d_ws;
    _Float16* w1l   = w1h + 32768;
    _Float16* w2h   = w1l + 32768;
    _Float16* w2l   = w2h + 32768;
    _Float16* qkBh  = (_Float16*)((char*)d_ws + 262144);
    _Float16* qkBl  = qkBh + 2048;
    float*    qb2G  = (float*)((char*)d_ws + 270336);
    float*    peG   = (float*)((char*)d_ws + 270400);
    float*    w_m0P = (float*)((char*)d_ws + M0P_OFF);
    float*    w_m1P = (float*)((char*)d_ws + M1P_OFF);
    float*    o_ws  = (float*)((char*)d_ws + OWS_OFF);

    hipLaunchKernelGGL(ltae_prep, dim3(524), dim3(256), 0, stream,
                       w_in0, w_in1, Qm, w_k, b_k, bpos, w_m0, w_m1,
                       w1h, w1l, w2h, w2l, qkBh, qkBl, qb2G, peG, w_m0P, w_m1P);

    hipLaunchKernelGGL(ltae_main, dim3(4608), dim3(256), 0, stream,
                       x,
                       b_in0, g_in0, be_in0,
                       b_in1, g_in1, be_in1,
                       g_innorm, b_innorm,
                       w1h, w1l, w2h, w2l, qkBh, qkBl, qb2G, peG,
                       o_ws);

    hipLaunchKernelGGL(ltae_mlp, dim3(1152), dim3(256), 0, stream,
                       o_ws,
                       w_m0P, b_m0, g_m0, be_m0,
                       w_m1P, b_m1, g_m1, be_m1,
                       g_out, b_out,
                       (float*)d_out);
}